// Round 12
// baseline (600.559 us; speedup 1.0000x reference)
//
#include <hip/hip_runtime.h>
#include <hip/hip_fp16.h>

#define NN 10000
#define FF 32
#define PG 4      // pairs per group
#define NGRP 24   // 96 pairs / PG

typedef __attribute__((ext_vector_type(2))) float f32x2;

__device__ __forceinline__ unsigned short f2h(float f){
  union { unsigned short s; _Float16 h; } c; c.h = (_Float16)f; return c.s;
}

// acc += w(f16 = lo half of packed VGPR word) * halves of h. One VOP3P each.
// op_sel_hi:[1,1,0] marks S0 AND S1 as f16; op_sel[1] picks S1's half.
__device__ __forceinline__ void fmix2v(float& ax, float& ay, unsigned wpk, unsigned h){
  asm("v_fma_mix_f32 %0, %2, %3, %0 op_sel_hi:[1,1,0]\n\t"
      "v_fma_mix_f32 %1, %2, %3, %1 op_sel:[0,1,0] op_sel_hi:[1,1,0]"
      : "+v"(ax), "+v"(ay) : "v"(wpk), "v"(h));
}
// f32 VGPR weight variant (self-loop dinv term, cndmask'd to 0 on hi half).
__device__ __forceinline__ void fmix2(float& ax, float& ay, float w, unsigned h){
  asm("v_fma_mix_f32 %0, %2, %3, %0 op_sel_hi:[0,1,0]\n\t"
      "v_fma_mix_f32 %1, %2, %3, %1 op_sel:[0,1,0] op_sel_hi:[0,1,0]"
      : "+v"(ax), "+v"(ay) : "v"(w), "v"(h));
}

// packed fp32 FMA for gemm1 (157 TF fp32 peak needs v_pk_fma_f32).
__device__ __forceinline__ void pkfma(f32x2& acc, f32x2 w, f32x2 x){
  asm("v_pk_fma_f32 %0, %1, %2, %0" : "+v"(acc) : "s"(w), "v"(x));
}

// ---- CSR build -------------------------------------------------------------
// csr entry (u32): (src << 16) | fp16(dinv[src]). Zeroed here: pad entries
// read row 0 with weight 0.0 -> harmless.
__global__ void k_count(const int* __restrict__ dst, int* __restrict__ cnt,
                        unsigned* __restrict__ csr, int csrcap, int E){
  int e = blockIdx.x * 256 + threadIdx.x;
  if (e >= E) return;
  csr[e] = 0u;
  int e2 = e + E;
  if (e2 < csrcap) csr[e2] = 0u;
  atomicAdd(&cnt[dst[e]], 1);
}

// Parallel prep: offsets via unordered atomicAdd allocation (row order is
// irrelevant); stores {start,end}. Blocks 40..44 compute W12/bb.
__global__ __launch_bounds__(256) void k_prep(const int* __restrict__ cnt,
    int2* __restrict__ oe, float* __restrict__ dinv, int* __restrict__ gtop,
    const float* __restrict__ W1, const float* __restrict__ W2,
    const float* __restrict__ b1, float* __restrict__ W12, float* __restrict__ bb){
  int bx = blockIdx.x, tid = threadIdx.x;
  if (bx < 40){
    int i = bx * 256 + tid;
    if (i < NN){
      int c = cnt[i];
      int pad = (c + 3) & ~3;
      int start = atomicAdd(gtop, pad);
      oe[i] = make_int2(start, start + pad);
      dinv[i] = rsqrtf((float)(c + 1));
    }
  } else {
    int j = (bx - 40) * 256 + tid;
    if (j < 33 * 32){
      int k = j >> 5, c = j & 31;
      float s = 0.f;
      for (int m = 0; m < 64; ++m) s += W1[k * 64 + m] * W2[m * 32 + c];
      W12[j] = s;
    } else if (j < 33 * 32 + 32){
      int c = j - 33 * 32;
      float s = 0.f;
      for (int m = 0; m < 64; ++m) s += b1[m] * W2[m * 32 + c];
      bb[c] = s;
    }
  }
}

// Also accumulates srow_acc[d] = sum of dinv[src] (agg2 reconstructs
// srow = dinv*(dinv+acc)).
__global__ void k_scatter(const int* __restrict__ ei, const int2* __restrict__ oe,
                          int* __restrict__ cur, const float* __restrict__ dinv,
                          unsigned* __restrict__ csr, float* __restrict__ srow, int E){
  int e = blockIdx.x * 256 + threadIdx.x;
  if (e >= E) return;
  int s = ei[e], d = ei[E + e];
  float ds = dinv[s];
  int pos = oe[d].x + atomicAdd(&cur[d], 1);
  csr[pos] = ((unsigned)s << 16) | (unsigned)f2h(ds);
  atomicAdd(&srow[d], ds);
}

// ---- GEMM1 v5: direct-to-LDS staging (global_load_lds) + XOR swizzle -------
__global__ __launch_bounds__(256) void k_gemm1(const float* __restrict__ x,
    const float* __restrict__ mask, const float* __restrict__ W12,
    unsigned* __restrict__ hw){
  __shared__ float xs[256][32];               // [node][feat], XOR-swizzled
  const int pg = blockIdx.y;                  // 0..95 (b*24+h)
  const int n0 = blockIdx.x * 256;
  const int t  = threadIdx.x;
  const int l  = t & 63;
  const int wv = __builtin_amdgcn_readfirstlane(t) >> 6;   // wave-uniform
  const int grp = pg >> 2, p = pg & 3;
  const float mv = mask[pg];
  const f32x2* Wp = (const f32x2*)W12;        // [33][16] feature pairs
  f32x2 acc[16];
  #pragma unroll
  for (int qf = 0; qf < 16; ++qf){
    f32x2 w = Wp[32 * 16 + qf];               // mask row
    acc[qf].x = mv * w.x; acc[qf].y = mv * w.y;
  }
  // stage: each wave issues 8 global_load_lds, each covering 8 rows (1 KB)
  const int rsub = l >> 3;                    // row within 8-row chunk
  const int qd   = (l & 7) ^ rsub;            // pre-swizzled source quad
  const float* xpg = x + (size_t)pg * (NN * FF);
  #pragma unroll
  for (int i = 0; i < 8; ++i){
    int chunk = wv * 8 + i;                   // 0..31, wave-uniform
    int grow = n0 + chunk * 8 + rsub;
    grow = grow < NN ? grow : NN - 1;         // clamp: dup rows unused
    const float* gsrc = xpg + (size_t)grow * FF + (qd << 2);
    char* ldst = (char*)&xs[0][0] + (chunk << 10);   // wave-uniform base
    __builtin_amdgcn_global_load_lds(
        (const __attribute__((address_space(1))) void*)gsrc,
        (__attribute__((address_space(3))) void*)ldst, 16, 0, 0);
  }
  asm volatile("s_waitcnt vmcnt(0)" ::: "memory");
  __syncthreads();
  const int n = n0 + t;
  if (n >= NN) return;
  const int sw = (t & 7) << 2;
  #pragma unroll
  for (int Q = 0; Q < 8; ++Q){
    float4 v = *(const float4*)&xs[t][(Q << 2) ^ sw];
    const float* vf = (const float*)&v;
    #pragma unroll
    for (int j = 0; j < 4; ++j){
      int k = (Q << 2) + j;
      f32x2 xk2; xk2.x = vf[j]; xk2.y = vf[j];
      #pragma unroll
      for (int qf = 0; qf < 16; ++qf) pkfma(acc[qf], Wp[k * 16 + qf], xk2);
    }
  }
  unsigned* hwg = hw + (size_t)grp * (NN * 64) + ((size_t)n << 6) + (p << 4);
  #pragma unroll
  for (int j = 0; j < 4; ++j){
    uint4 u;
    u.x = (unsigned)f2h(acc[4*j+0].x) | ((unsigned)f2h(acc[4*j+0].y) << 16);
    u.y = (unsigned)f2h(acc[4*j+1].x) | ((unsigned)f2h(acc[4*j+1].y) << 16);
    u.z = (unsigned)f2h(acc[4*j+2].x) | ((unsigned)f2h(acc[4*j+2].y) << 16);
    u.w = (unsigned)f2h(acc[4*j+3].x) | ((unsigned)f2h(acc[4*j+3].y) << 16);
    ((uint4*)hwg)[j] = u;
  }
}

// ---- block->group mapping: pin each group to one XCD (blockIdx%8) ----------
__device__ __forceinline__ void map_block(int bx, int& grp, int& chunk){
  int r  = bx / 5000;       // 0..2
  int w8 = bx % 5000;
  grp   = r * 8 + (w8 & 7);
  chunk = w8 >> 3;          // 0..624
}

// ---- dwordx2 half-split edge aggregation -----------------------------------
// One gather instruction now serves TWO edges: lanes 0-31 read the full 256-B
// row of the even edge (8 B/lane), lanes 32-63 the odd edge. Gather (TA)
// instructions per pass halve (8M -> 4M); bytes/lines/coalescing unchanged
// (two dense 256-B segments per instr). Each lane accumulates 4 features
// (dwords 2j, 2j+1); a single __shfl_xor(.,32) per node merges the halves.
// Weights are per-half -> v_cndmask into VGPR, consumed by fma_mix as f16-lo.
// csr walk unchanged from r9: SGPR s_load_dwordx4, 3-stage window, batched.
#define ROWB(w) ((((unsigned)(w)) >> 8) & 0xFFFF00u)
__device__ __forceinline__ void agg_edges(int e0, int e1,
    const unsigned* __restrict__ csr, const char* __restrict__ Vb, int loff,
    bool hi, float& ax0, float& ay0, float& ax1, float& ay1){
  int nq = (e1 - e0) >> 2;
  if (nq <= 0) return;
  const int4* c4 = (const int4*)(csr + e0);   // 16 B per quad (4 edges)
  const int qlast = nq - 1;
  #define V2LD(w) (*(const uint2*)(Vb + (unsigned)(ROWB(w) + loff)))
  int4 cA2, cB2, cC2, cD2;      // csr quads q+4..q+7 (refill source)
  int4 cA3, cB3, cC3, cD3;      // csr quads q+8..q+11 (in-flight window)
  unsigned wA0,wA1, wB0,wB1, wC0,wC1, wD0,wD1;  // per-lane packed words
  uint2 rA0,rA1, rB0,rB1, rC0,rC1, rD0,rD1;     // gather results (2 dwords)
  {
    int i1 = 1<=qlast?1:qlast, i2 = 2<=qlast?2:qlast, i3 = 3<=qlast?3:qlast;
    int4 cA = c4[0], cB = c4[i1], cC = c4[i2], cD = c4[i3];
    wA0 = hi ? (unsigned)cA.y : (unsigned)cA.x;
    wA1 = hi ? (unsigned)cA.w : (unsigned)cA.z;
    wB0 = hi ? (unsigned)cB.y : (unsigned)cB.x;
    wB1 = hi ? (unsigned)cB.w : (unsigned)cB.z;
    wC0 = hi ? (unsigned)cC.y : (unsigned)cC.x;
    wC1 = hi ? (unsigned)cC.w : (unsigned)cC.z;
    wD0 = hi ? (unsigned)cD.y : (unsigned)cD.x;
    wD1 = hi ? (unsigned)cD.w : (unsigned)cD.z;
    rA0 = V2LD(wA0); rA1 = V2LD(wA1);
    rB0 = V2LD(wB0); rB1 = V2LD(wB1);
    rC0 = V2LD(wC0); rC1 = V2LD(wC1);
    rD0 = V2LD(wD0); rD1 = V2LD(wD1);
    int i4 = 4<=qlast?4:qlast, i5 = 5<=qlast?5:qlast;
    int i6 = 6<=qlast?6:qlast, i7 = 7<=qlast?7:qlast;
    cA2 = c4[i4]; cB2 = c4[i5]; cC2 = c4[i6]; cD2 = c4[i7];
    int i8 = 8<=qlast?8:qlast, i9 = 9<=qlast?9:qlast;
    int i10 = 10<=qlast?10:qlast, i11 = 11<=qlast?11:qlast;
    cA3 = c4[i8]; cB3 = c4[i9]; cC3 = c4[i10]; cD3 = c4[i11];
  }
  int q = 0;
  #define AGG_STEP(w0, w1, r0, r1, cX2, cX3)                            \
    do {                                                                \
      fmix2v(ax0, ay0, w0, r0.x); fmix2v(ax1, ay1, w0, r0.y);           \
      fmix2v(ax0, ay0, w1, r1.x); fmix2v(ax1, ay1, w1, r1.y);           \
      w0 = hi ? (unsigned)cX2.y : (unsigned)cX2.x;                      \
      w1 = hi ? (unsigned)cX2.w : (unsigned)cX2.z;                      \
      r0 = V2LD(w0); r1 = V2LD(w1);                                     \
      cX2 = cX3;                                                        \
    } while (0)
  for (; q + 3 < nq; q += 4){
    AGG_STEP(wA0, wA1, rA0, rA1, cA2, cA3);
    AGG_STEP(wB0, wB1, rB0, rB1, cB2, cB3);
    AGG_STEP(wC0, wC1, rC0, rC1, cC2, cC3);
    AGG_STEP(wD0, wD1, rD0, rD1, cD2, cD3);
    int j0 = q+12 <= qlast ? q+12 : qlast;
    int j1 = q+13 <= qlast ? q+13 : qlast;
    int j2 = q+14 <= qlast ? q+14 : qlast;
    int j3 = q+15 <= qlast ? q+15 : qlast;
    cA3 = c4[j0]; cB3 = c4[j1]; cC3 = c4[j2]; cD3 = c4[j3];
  }
  #undef AGG_STEP
  #undef V2LD
  int rem = nq - q;   // 0..3 (wave-uniform)
  if (rem > 0){
    fmix2v(ax0, ay0, wA0, rA0.x); fmix2v(ax1, ay1, wA0, rA0.y);
    fmix2v(ax0, ay0, wA1, rA1.x); fmix2v(ax1, ay1, wA1, rA1.y);
  }
  if (rem > 1){
    fmix2v(ax0, ay0, wB0, rB0.x); fmix2v(ax1, ay1, wB0, rB0.y);
    fmix2v(ax0, ay0, wB1, rB1.x); fmix2v(ax1, ay1, wB1, rB1.y);
  }
  if (rem > 2){
    fmix2v(ax0, ay0, wC0, rC0.x); fmix2v(ax1, ay1, wC0, rC0.y);
    fmix2v(ax0, ay0, wC1, rC1.x); fmix2v(ax1, ay1, wC1, rC1.y);
  }
}

// ---- agg layer 1: t1 = A*hw (fp16 rows, fp32 accum) ------------------------
__global__ __launch_bounds__(256) void k_agg1(const int2* __restrict__ oe,
    const unsigned* __restrict__ csr, const float* __restrict__ dinv,
    const unsigned int* __restrict__ V, unsigned int* __restrict__ T){
  int grp, chunk; map_block(blockIdx.x, grp, chunk);
  int tid = threadIdx.x;
  int l = tid & 63, j = l & 31;
  bool hi = l >= 32;
  int wv = __builtin_amdgcn_readfirstlane(tid) >> 6;   // wave-uniform
  const char* Vb = (const char*)(V + (size_t)grp * (NN * 64));
  unsigned int* Tg = T + (size_t)grp * (NN * 64);
  int loff = j * 8;
  for (int it = 0; it < 4; ++it){
    int n = chunk * 16 + wv * 4 + it;
    float din = dinv[n];
    int2 ee = oe[n];
    uint2 sv = *(const uint2*)(Vb + (unsigned)((n << 8) + loff));
    float ax0 = 0.f, ay0 = 0.f, ax1 = 0.f, ay1 = 0.f;
    float wself = hi ? 0.f : din;    // self-loop counted once (low half)
    fmix2(ax0, ay0, wself, sv.x);
    fmix2(ax1, ay1, wself, sv.y);
    agg_edges(ee.x, ee.y, csr, Vb, loff, hi, ax0, ay0, ax1, ay1);
    ax0 += __shfl_xor(ax0, 32); ay0 += __shfl_xor(ay0, 32);
    ax1 += __shfl_xor(ax1, 32); ay1 += __shfl_xor(ay1, 32);
    if (!hi){
      uint2 u;
      u.x = (unsigned)f2h(din * ax0) | ((unsigned)f2h(din * ay0) << 16);
      u.y = (unsigned)f2h(din * ax1) | ((unsigned)f2h(din * ay1) << 16);
      *(uint2*)(Tg + (((size_t)n) << 6) + (j << 1)) = u;
    }
  }
}

// ---- agg layer 2 + epilogue: out = tanh(A*t1 + srow*bb + b2) fp32 ----------
__global__ __launch_bounds__(256) void k_agg2(const int2* __restrict__ oe,
    const unsigned* __restrict__ csr, const float* __restrict__ dinv,
    const float* __restrict__ srow, const float* __restrict__ bb,
    const float* __restrict__ b2, const unsigned int* __restrict__ V,
    float* __restrict__ out){
  int grp, chunk; map_block(blockIdx.x, grp, chunk);
  int tid = threadIdx.x;
  int l = tid & 63, j = l & 31;
  bool hi = l >= 32;
  int wv = __builtin_amdgcn_readfirstlane(tid) >> 6;
  const char* Vb = (const char*)(V + (size_t)grp * (NN * 64));
  float4 bb4 = ((const float4*)bb)[j & 7];
  float4 b24 = ((const float4*)b2)[j & 7];
  int pg = grp * PG + (j >> 3);
  float* outp = out + (size_t)pg * (NN * FF);
  int loff = j * 8;
  for (int it = 0; it < 4; ++it){
    int n = chunk * 16 + wv * 4 + it;
    float din = dinv[n];
    int2 ee = oe[n];
    uint2 sv = *(const uint2*)(Vb + (unsigned)((n << 8) + loff));
    float ax0 = 0.f, ay0 = 0.f, ax1 = 0.f, ay1 = 0.f;
    float wself = hi ? 0.f : din;
    fmix2(ax0, ay0, wself, sv.x);
    fmix2(ax1, ay1, wself, sv.y);
    agg_edges(ee.x, ee.y, csr, Vb, loff, hi, ax0, ay0, ax1, ay1);
    ax0 += __shfl_xor(ax0, 32); ay0 += __shfl_xor(ay0, 32);
    ax1 += __shfl_xor(ax1, 32); ay1 += __shfl_xor(ay1, 32);
    if (!hi){
      float sr = din * (din + srow[n]);   // srow from scatter accumulation
      float4 o;
      o.x = tanhf(din * ax0 + sr * bb4.x + b24.x);
      o.y = tanhf(din * ay0 + sr * bb4.y + b24.y);
      o.z = tanhf(din * ax1 + sr * bb4.z + b24.z);
      o.w = tanhf(din * ay1 + sr * bb4.w + b24.w);
      ((float4*)(outp + (size_t)n * FF))[j & 7] = o;
    }
  }
}

extern "C" void kernel_launch(void* const* d_in, const int* in_sizes, int n_in,
                              void* d_out, int out_size, void* d_ws, size_t ws_size,
                              hipStream_t stream){
  const float* x    = (const float*)d_in[0];
  const float* mask = (const float*)d_in[1];
  const int*   ei   = (const int*)d_in[2];
  const float* W1   = (const float*)d_in[3];
  const float* b1   = (const float*)d_in[4];
  const float* W2   = (const float*)d_in[5];
  const float* b2   = (const float*)d_in[6];
  float* out = (float*)d_out;
  const int E = in_sizes[2] / 2;   // 320000
  const int CSRCAP = E + 3 * NN + 64;  // padded-to-4 worst case + slack (entries)

  char* wsp = (char*)d_ws;
  auto alloc = [&](size_t bytes) -> char* {
    char* p = wsp; wsp += (bytes + 255) & ~(size_t)255; return p;
  };
  // zero-span buffers first (cnt..gtop zeroed by ONE memset)
  int*   cnt  = (int*)  alloc((size_t)NN * 4);
  int*   cur  = (int*)  alloc((size_t)NN * 4);
  float* srow = (float*)alloc((size_t)NN * 4);
  int*   gtop = (int*)  alloc(256);
  float* dinv = (float*)alloc((size_t)NN * 4);
  int2*  oe   = (int2*) alloc((size_t)NN * 8);
  float* W12  = (float*)alloc(33 * 32 * 4);
  float* bbv  = (float*)alloc(32 * 4);
  unsigned* csr = (unsigned*)alloc((size_t)CSRCAP * 4);
  const size_t per_group = (size_t)NN * 64 * 4;    // [n][4p][32f] fp16 = 2.56MB
  unsigned int* hw = (unsigned int*)alloc((size_t)NGRP * per_group);
  unsigned int* t1 = (unsigned int*)alloc((size_t)NGRP * per_group);

  size_t zspan = (size_t)((char*)dinv - (char*)cnt);
  hipMemsetAsync(cnt, 0, zspan, stream);               // cnt+cur+srow+gtop
  k_count  <<<(E + 255) / 256, 256, 0, stream>>>(ei + E, cnt, csr, CSRCAP, E);
  k_prep   <<<45, 256, 0, stream>>>(cnt, oe, dinv, gtop, W1, W2, b1, W12, bbv);
  k_scatter<<<(E + 255) / 256, 256, 0, stream>>>(ei, oe, cur, dinv, csr, srow, E);

  k_gemm1<<<dim3(40, 96), 256, 0, stream>>>(x, mask, W12, hw);
  k_agg1 <<<15000, 256, 0, stream>>>(oe, csr, dinv, hw, t1);
  k_agg2 <<<15000, 256, 0, stream>>>(oe, csr, dinv, srow, bbv, b2, t1, out);
}

// Round 13
// 474.633 us; speedup vs baseline: 1.2653x; 1.2653x over previous
//
#include <hip/hip_runtime.h>
#include <hip/hip_fp16.h>

#define NN 10000
#define FF 32
#define PG 4      // pairs per group
#define NGRP 24   // 96 pairs / PG

typedef __attribute__((ext_vector_type(2))) float f32x2;

__device__ __forceinline__ unsigned short f2h(float f){
  union { unsigned short s; _Float16 h; } c; c.h = (_Float16)f; return c.s;
}

// acc += w(f16, lo half of packed SGPR word) * halves of h. One VOP3P each.
// op_sel_hi:[1,1,0] marks S0 AND S1 as f16; op_sel[1] picks S1's half.
// S0 = wave-uniform packed csr word -> SGPR operand, zero VALU for weights.
__device__ __forceinline__ void fmix2p(float& ax, float& ay, unsigned wpk, unsigned h){
  asm("v_fma_mix_f32 %0, %2, %3, %0 op_sel_hi:[1,1,0]\n\t"
      "v_fma_mix_f32 %1, %2, %3, %1 op_sel:[0,1,0] op_sel_hi:[1,1,0]"
      : "+v"(ax), "+v"(ay) : "s"(wpk), "v"(h));
}
// f32 SGPR weight variant (self-loop dinv term).
__device__ __forceinline__ void fmix2s(float& ax, float& ay, float w, unsigned h){
  asm("v_fma_mix_f32 %0, %2, %3, %0 op_sel_hi:[0,1,0]\n\t"
      "v_fma_mix_f32 %1, %2, %3, %1 op_sel:[0,1,0] op_sel_hi:[0,1,0]"
      : "+v"(ax), "+v"(ay) : "s"(w), "v"(h));
}

// packed fp32 FMA for gemm1 (157 TF fp32 peak needs v_pk_fma_f32).
__device__ __forceinline__ void pkfma(f32x2& acc, f32x2 w, f32x2 x){
  asm("v_pk_fma_f32 %0, %1, %2, %0" : "+v"(acc) : "s"(w), "v"(x));
}

// ---- CSR build -------------------------------------------------------------
// csr entry (u32): (src << 16) | fp16(dinv[src]). csr zeroed by the launch
// memset (pad entries read row 0 with weight 0.0 -> harmless).
__global__ void k_count(const int* __restrict__ dst, int* __restrict__ cnt, int E){
  int e = blockIdx.x * 256 + threadIdx.x;
  if (e < E) atomicAdd(&cnt[dst[e]], 1);
}

// Parallel prep: offsets via unordered atomicAdd allocation (row order is
// irrelevant); stores {start,end}. Blocks 40..44 compute W12/bb.
__global__ __launch_bounds__(256) void k_prep(const int* __restrict__ cnt,
    int2* __restrict__ oe, float* __restrict__ dinv, int* __restrict__ gtop,
    const float* __restrict__ W1, const float* __restrict__ W2,
    const float* __restrict__ b1, float* __restrict__ W12, float* __restrict__ bb){
  int bx = blockIdx.x, tid = threadIdx.x;
  if (bx < 40){
    int i = bx * 256 + tid;
    if (i < NN){
      int c = cnt[i];
      int pad = (c + 3) & ~3;
      int start = atomicAdd(gtop, pad);
      oe[i] = make_int2(start, start + pad);
      dinv[i] = rsqrtf((float)(c + 1));
    }
  } else {
    int j = (bx - 40) * 256 + tid;
    if (j < 33 * 32){
      int k = j >> 5, c = j & 31;
      float s = 0.f;
      for (int m = 0; m < 64; ++m) s += W1[k * 64 + m] * W2[m * 32 + c];
      W12[j] = s;
    } else if (j < 33 * 32 + 32){
      int c = j - 33 * 32;
      float s = 0.f;
      for (int m = 0; m < 64; ++m) s += b1[m] * W2[m * 32 + c];
      bb[c] = s;
    }
  }
}

// ---- FUSED scatter + GEMM1 dispatch ----------------------------------------
// scatter (blocks [0,SB)) and gemm1 (blocks [SB,SB+3840)) are independent:
// scatter writes csr/srow/cur from ei/oe/dinv; gemm1 reads x/mask/W12 and
// writes hw. One dispatch overlaps scatter's atomic tail under gemm1's
// compute and removes a launch gap.
// GEMM1 v5 path: direct-to-LDS staging (global_load_lds, width=16) with the
// XOR bank swizzle riding on the SOURCE address (linear LDS dest), conflict-
// free ds_read_b128 on the XOR'd read side. LDS = 32 KiB exactly.
__global__ __launch_bounds__(256) void k_fused(
    const int* __restrict__ ei, const int2* __restrict__ oe,
    int* __restrict__ cur, const float* __restrict__ dinv,
    unsigned* __restrict__ csr, float* __restrict__ srow, int E, int SB,
    const float* __restrict__ x, const float* __restrict__ mask,
    const float* __restrict__ W12, unsigned* __restrict__ hw){
  __shared__ float xs[256][32];               // [node][feat], XOR-swizzled
  const int bx = blockIdx.x;
  const int t  = threadIdx.x;
  if (bx < SB){
    // ---- scatter path (also accumulates srow_acc[d] = sum dinv[src]) ----
    int e = bx * 256 + t;
    if (e >= E) return;
    int s = ei[e], d = ei[E + e];
    float ds = dinv[s];
    int pos = oe[d].x + atomicAdd(&cur[d], 1);
    csr[pos] = ((unsigned)s << 16) | (unsigned)f2h(ds);
    atomicAdd(&srow[d], ds);
    return;
  }
  // ---- gemm1 path ----
  const int g  = bx - SB;                     // 0..3839
  const int pg = g / 40;                      // 0..95 (b*24+h)
  const int n0 = (g % 40) * 256;
  const int l  = t & 63;
  const int wv = __builtin_amdgcn_readfirstlane(t) >> 6;   // wave-uniform
  const int grp = pg >> 2, p = pg & 3;
  const float mv = mask[pg];
  const f32x2* Wp = (const f32x2*)W12;        // [33][16] feature pairs
  f32x2 acc[16];
  #pragma unroll
  for (int qf = 0; qf < 16; ++qf){
    f32x2 w = Wp[32 * 16 + qf];               // mask row
    acc[qf].x = mv * w.x; acc[qf].y = mv * w.y;
  }
  // stage: each wave issues 8 global_load_lds, each covering 8 rows (1 KB)
  const int rsub = l >> 3;                    // row within 8-row chunk
  const int qd   = (l & 7) ^ rsub;            // pre-swizzled source quad
  const float* xpg = x + (size_t)pg * (NN * FF);
  #pragma unroll
  for (int i = 0; i < 8; ++i){
    int chunk = wv * 8 + i;                   // 0..31, wave-uniform
    int grow = n0 + chunk * 8 + rsub;
    grow = grow < NN ? grow : NN - 1;         // clamp: dup rows unused
    const float* gsrc = xpg + (size_t)grow * FF + (qd << 2);
    char* ldst = (char*)&xs[0][0] + (chunk << 10);   // wave-uniform base
    __builtin_amdgcn_global_load_lds(
        (const __attribute__((address_space(1))) void*)gsrc,
        (__attribute__((address_space(3))) void*)ldst, 16, 0, 0);
  }
  asm volatile("s_waitcnt vmcnt(0)" ::: "memory");
  __syncthreads();
  const int n = n0 + t;
  if (n >= NN) return;
  const int sw = (t & 7) << 2;
  #pragma unroll
  for (int Q = 0; Q < 8; ++Q){
    float4 v = *(const float4*)&xs[t][(Q << 2) ^ sw];
    const float* vf = (const float*)&v;
    #pragma unroll
    for (int j = 0; j < 4; ++j){
      int k = (Q << 2) + j;
      f32x2 xk2; xk2.x = vf[j]; xk2.y = vf[j];
      #pragma unroll
      for (int qf = 0; qf < 16; ++qf) pkfma(acc[qf], Wp[k * 16 + qf], xk2);
    }
  }
  unsigned* hwg = hw + (size_t)grp * (NN * 64) + ((size_t)n << 6) + (p << 4);
  #pragma unroll
  for (int j = 0; j < 4; ++j){
    uint4 u;
    u.x = (unsigned)f2h(acc[4*j+0].x) | ((unsigned)f2h(acc[4*j+0].y) << 16);
    u.y = (unsigned)f2h(acc[4*j+1].x) | ((unsigned)f2h(acc[4*j+1].y) << 16);
    u.z = (unsigned)f2h(acc[4*j+2].x) | ((unsigned)f2h(acc[4*j+2].y) << 16);
    u.w = (unsigned)f2h(acc[4*j+3].x) | ((unsigned)f2h(acc[4*j+3].y) << 16);
    ((uint4*)hwg)[j] = u;
  }
}

// ---- block->group mapping: pin each group to one XCD (blockIdx%8) ----------
// One group slice (2.56 MB) per XCD at a time -> gathers stay L2-resident.
// (Tested & rejected: 3-group fusion r3 (L2 blowup), r-split x3 r10 (dispatch
// tails), dwordx2 half-split r12 (2 rows/instr = same line count + VALU).
__device__ __forceinline__ void map_block(int bx, int& grp, int& chunk){
  int r  = bx / 5000;       // 0..2
  int w8 = bx % 5000;
  grp   = r * 8 + (w8 & 7);
  chunk = w8 >> 3;          // 0..624
}

// ---- 4-deep pipelined edge accumulation, packed csr, batched s_loads -------
// (r11 best: agg2 ~108.8us; five micro-variants tried, all <=3us or worse ->
// treated as this structure's floor: ~2x random-granule L2 ceiling.)
#define ROWB(w) ((((unsigned)(w)) >> 8) & 0xFFFF00u)
__device__ __forceinline__ void agg_edges(int e0, int e1,
    const unsigned* __restrict__ csr, const char* __restrict__ Vb, int loff,
    float& ax, float& ay){
  int nq = (e1 - e0) >> 2;
  if (nq <= 0) return;
  const int4* c4 = (const int4*)(csr + e0);   // 16 B per quad
  const int qlast = nq - 1;
  #define VLD(w) (*(const unsigned*)(Vb + (unsigned)(ROWB(w) + loff)))
  int4 cA, cB, cC, cD;          // csr quads q..q+3   (fmix source)
  int4 cA2, cB2, cC2, cD2;      // csr quads q+4..q+7 (gather-address source)
  int4 cA3, cB3, cC3, cD3;      // csr quads q+8..q+11 (in-flight window)
  unsigned rA0,rA1,rA2,rA3, rB0,rB1,rB2,rB3;
  unsigned rC0,rC1,rC2,rC3, rD0,rD1,rD2,rD3;
  {
    int i1 = 1<=qlast?1:qlast, i2 = 2<=qlast?2:qlast, i3 = 3<=qlast?3:qlast;
    cA = c4[0]; cB = c4[i1]; cC = c4[i2]; cD = c4[i3];
    int i4 = 4<=qlast?4:qlast, i5 = 5<=qlast?5:qlast;
    int i6 = 6<=qlast?6:qlast, i7 = 7<=qlast?7:qlast;
    cA2 = c4[i4]; cB2 = c4[i5]; cC2 = c4[i6]; cD2 = c4[i7];
    int i8 = 8<=qlast?8:qlast, i9 = 9<=qlast?9:qlast;
    int i10 = 10<=qlast?10:qlast, i11 = 11<=qlast?11:qlast;
    cA3 = c4[i8]; cB3 = c4[i9]; cC3 = c4[i10]; cD3 = c4[i11];
    rA0 = VLD(cA.x); rA1 = VLD(cA.y); rA2 = VLD(cA.z); rA3 = VLD(cA.w);
    rB0 = VLD(cB.x); rB1 = VLD(cB.y); rB2 = VLD(cB.z); rB3 = VLD(cB.w);
    rC0 = VLD(cC.x); rC1 = VLD(cC.y); rC2 = VLD(cC.z); rC3 = VLD(cC.w);
    rD0 = VLD(cD.x); rD1 = VLD(cD.y); rD2 = VLD(cD.z); rD3 = VLD(cD.w);
  }
  int q = 0;
  #define AGG_STEP(cX, cX2, cX3, r0, r1, r2, r3)                        \
    do {                                                                \
      fmix2p(ax, ay, (unsigned)cX.x, r0);                               \
      fmix2p(ax, ay, (unsigned)cX.y, r1);                               \
      fmix2p(ax, ay, (unsigned)cX.z, r2);                               \
      fmix2p(ax, ay, (unsigned)cX.w, r3);                               \
      r0 = VLD(cX2.x); r1 = VLD(cX2.y);                                 \
      r2 = VLD(cX2.z); r3 = VLD(cX2.w);                                 \
      cX = cX2; cX2 = cX3;                                              \
    } while (0)
  for (; q + 3 < nq; q += 4){
    AGG_STEP(cA, cA2, cA3, rA0,rA1,rA2,rA3);
    AGG_STEP(cB, cB2, cB3, rB0,rB1,rB2,rB3);
    AGG_STEP(cC, cC2, cC3, rC0,rC1,rC2,rC3);
    AGG_STEP(cD, cD2, cD3, rD0,rD1,rD2,rD3);
    int j0 = q+12 <= qlast ? q+12 : qlast;
    int j1 = q+13 <= qlast ? q+13 : qlast;
    int j2 = q+14 <= qlast ? q+14 : qlast;
    int j3 = q+15 <= qlast ? q+15 : qlast;
    cA3 = c4[j0]; cB3 = c4[j1]; cC3 = c4[j2]; cD3 = c4[j3];
  }
  #undef AGG_STEP
  #undef VLD
  int rem = nq - q;   // 0..3 (wave-uniform)
  if (rem > 0){
    fmix2p(ax, ay, (unsigned)cA.x, rA0);
    fmix2p(ax, ay, (unsigned)cA.y, rA1);
    fmix2p(ax, ay, (unsigned)cA.z, rA2);
    fmix2p(ax, ay, (unsigned)cA.w, rA3);
  }
  if (rem > 1){
    fmix2p(ax, ay, (unsigned)cB.x, rB0);
    fmix2p(ax, ay, (unsigned)cB.y, rB1);
    fmix2p(ax, ay, (unsigned)cB.z, rB2);
    fmix2p(ax, ay, (unsigned)cB.w, rB3);
  }
  if (rem > 2){
    fmix2p(ax, ay, (unsigned)cC.x, rC0);
    fmix2p(ax, ay, (unsigned)cC.y, rC1);
    fmix2p(ax, ay, (unsigned)cC.z, rC2);
    fmix2p(ax, ay, (unsigned)cC.w, rC3);
  }
}

// ---- agg layer 1: t1 = A*hw (fp16 rows, fp32 accum) ------------------------
__global__ __launch_bounds__(256) void k_agg1(const int2* __restrict__ oe,
    const unsigned* __restrict__ csr, const float* __restrict__ dinv,
    const unsigned int* __restrict__ V, unsigned int* __restrict__ T){
  int grp, chunk; map_block(blockIdx.x, grp, chunk);
  int tid = threadIdx.x;
  int l = tid & 63;
  int wv = __builtin_amdgcn_readfirstlane(tid) >> 6;   // wave-uniform
  const char* Vb = (const char*)(V + (size_t)grp * (NN * 64));
  unsigned int* Tg = T + (size_t)grp * (NN * 64);
  int loff = l * 4;
  for (int it = 0; it < 4; ++it){
    int n = chunk * 16 + wv * 4 + it;
    float din = dinv[n];
    int2 ee = oe[n];
    unsigned sv = *(const unsigned*)(Vb + (unsigned)((n << 8) + loff));
    float ax = 0.f, ay = 0.f;
    fmix2s(ax, ay, din, sv);
    agg_edges(ee.x, ee.y, csr, Vb, loff, ax, ay);
    Tg[((size_t)n << 6) + l] =
        (unsigned)f2h(din * ax) | ((unsigned)f2h(din * ay) << 16);
  }
}

// ---- agg layer 2 + epilogue: out = tanh(A*t1 + srow*bb + b2) fp32 ----------
__global__ __launch_bounds__(256) void k_agg2(const int2* __restrict__ oe,
    const unsigned* __restrict__ csr, const float* __restrict__ dinv,
    const float* __restrict__ srow, const float* __restrict__ bb,
    const float* __restrict__ b2, const unsigned int* __restrict__ V,
    float* __restrict__ out){
  int grp, chunk; map_block(blockIdx.x, grp, chunk);
  int tid = threadIdx.x;
  int l = tid & 63;
  int wv = __builtin_amdgcn_readfirstlane(tid) >> 6;
  int p = l >> 4, fi = l & 15;
  const char* Vb = (const char*)(V + (size_t)grp * (NN * 64));
  int pg = grp * PG + p;
  float2 bbq = ((const float2*)bb)[fi];
  float2 b2q = ((const float2*)b2)[fi];
  float* outp = out + (size_t)pg * (NN * FF);
  int loff = l * 4;
  for (int it = 0; it < 4; ++it){
    int n = chunk * 16 + wv * 4 + it;
    float din = dinv[n];
    int2 ee = oe[n];
    unsigned sv = *(const unsigned*)(Vb + (unsigned)((n << 8) + loff));
    float ax = 0.f, ay = 0.f;
    fmix2s(ax, ay, din, sv);
    agg_edges(ee.x, ee.y, csr, Vb, loff, ax, ay);
    float sr = din * (din + srow[n]);   // srow reconstructed from scatter acc
    float2 o;
    o.x = tanhf(din * ax + sr * bbq.x + b2q.x);
    o.y = tanhf(din * ay + sr * bbq.y + b2q.y);
    ((float2*)(outp + (size_t)n * FF))[fi] = o;
  }
}

extern "C" void kernel_launch(void* const* d_in, const int* in_sizes, int n_in,
                              void* d_out, int out_size, void* d_ws, size_t ws_size,
                              hipStream_t stream){
  const float* x    = (const float*)d_in[0];
  const float* mask = (const float*)d_in[1];
  const int*   ei   = (const int*)d_in[2];
  const float* W1   = (const float*)d_in[3];
  const float* b1   = (const float*)d_in[4];
  const float* W2   = (const float*)d_in[5];
  const float* b2   = (const float*)d_in[6];
  float* out = (float*)d_out;
  const int E = in_sizes[2] / 2;   // 320000
  const int CSRCAP = E + 3 * NN + 64;  // padded-to-4 worst case + slack (entries)
  const int SB = (E + 255) / 256;      // scatter blocks

  char* wsp = (char*)d_ws;
  auto alloc = [&](size_t bytes) -> char* {
    char* p = wsp; wsp += (bytes + 255) & ~(size_t)255; return p;
  };
  // zero-span buffers first (cnt..csr zeroed by ONE memset)
  int*   cnt  = (int*)  alloc((size_t)NN * 4);
  int*   cur  = (int*)  alloc((size_t)NN * 4);
  float* srow = (float*)alloc((size_t)NN * 4);
  int*   gtop = (int*)  alloc(256);
  unsigned* csr = (unsigned*)alloc((size_t)CSRCAP * 4);
  float* dinv = (float*)alloc((size_t)NN * 4);
  int2*  oe   = (int2*) alloc((size_t)NN * 8);
  float* W12  = (float*)alloc(33 * 32 * 4);
  float* bbv  = (float*)alloc(32 * 4);
  const size_t per_group = (size_t)NN * 64 * 4;    // [n][4p][32f] fp16 = 2.56MB
  unsigned int* hw = (unsigned int*)alloc((size_t)NGRP * per_group);
  unsigned int* t1 = (unsigned int*)alloc((size_t)NGRP * per_group);

  size_t zspan = (size_t)((char*)dinv - (char*)cnt);
  hipMemsetAsync(cnt, 0, zspan, stream);               // cnt+cur+srow+gtop+csr
  k_count<<<SB, 256, 0, stream>>>(ei + E, cnt, E);
  k_prep <<<45, 256, 0, stream>>>(cnt, oe, dinv, gtop, W1, W2, b1, W12, bbv);
  k_fused<<<SB + 3840, 256, 0, stream>>>(ei, oe, cur, dinv, csr, srow, E, SB,
                                         x, mask, W12, hw);
  k_agg1 <<<15000, 256, 0, stream>>>(oe, csr, dinv, hw, t1);
  k_agg2 <<<15000, 256, 0, stream>>>(oe, csr, dinv, srow, bbv, b2, t1, out);
}

// Round 14
// 472.091 us; speedup vs baseline: 1.2721x; 1.0054x over previous
//
#include <hip/hip_runtime.h>
#include <hip/hip_fp16.h>

#define NN 10000
#define FF 32
#define PG 4      // pairs per group
#define NGRP 24   // 96 pairs / PG

typedef __attribute__((ext_vector_type(2))) float f32x2;

__device__ __forceinline__ unsigned short f2h(float f){
  union { unsigned short s; _Float16 h; } c; c.h = (_Float16)f; return c.s;
}

// acc += w(f16, lo half of packed SGPR word) * halves of h. One VOP3P each.
// op_sel_hi:[1,1,0] marks S0 AND S1 as f16; op_sel[1] picks S1's half.
// S0 = wave-uniform packed csr word -> SGPR operand, zero VALU for weights.
__device__ __forceinline__ void fmix2p(float& ax, float& ay, unsigned wpk, unsigned h){
  asm("v_fma_mix_f32 %0, %2, %3, %0 op_sel_hi:[1,1,0]\n\t"
      "v_fma_mix_f32 %1, %2, %3, %1 op_sel:[0,1,0] op_sel_hi:[1,1,0]"
      : "+v"(ax), "+v"(ay) : "s"(wpk), "v"(h));
}
// f32 SGPR weight variant (self-loop dinv term).
__device__ __forceinline__ void fmix2s(float& ax, float& ay, float w, unsigned h){
  asm("v_fma_mix_f32 %0, %2, %3, %0 op_sel_hi:[0,1,0]\n\t"
      "v_fma_mix_f32 %1, %2, %3, %1 op_sel:[0,1,0] op_sel_hi:[0,1,0]"
      : "+v"(ax), "+v"(ay) : "s"(w), "v"(h));
}

// packed fp32 FMA for gemm1 (157 TF fp32 peak needs v_pk_fma_f32).
__device__ __forceinline__ void pkfma(f32x2& acc, f32x2 w, f32x2 x){
  asm("v_pk_fma_f32 %0, %1, %2, %0" : "+v"(acc) : "s"(w), "v"(x));
}

// ---- CSR build -------------------------------------------------------------
// csr entry (u32): (src << 16) | fp16(dinv[src]). csr zeroed by the launch
// memset (pad entries read row 0 with weight 0.0 -> harmless).
__global__ void k_count(const int* __restrict__ dst, int* __restrict__ cnt, int E){
  int e = blockIdx.x * 256 + threadIdx.x;
  if (e < E) atomicAdd(&cnt[dst[e]], 1);
}

// Parallel prep: offsets via unordered atomicAdd allocation (row order is
// irrelevant); stores {start,end}. Blocks 40..44 compute W12/bb.
__global__ __launch_bounds__(256) void k_prep(const int* __restrict__ cnt,
    int2* __restrict__ oe, float* __restrict__ dinv, int* __restrict__ gtop,
    const float* __restrict__ W1, const float* __restrict__ W2,
    const float* __restrict__ b1, float* __restrict__ W12, float* __restrict__ bb){
  int bx = blockIdx.x, tid = threadIdx.x;
  if (bx < 40){
    int i = bx * 256 + tid;
    if (i < NN){
      int c = cnt[i];
      int pad = (c + 3) & ~3;
      int start = atomicAdd(gtop, pad);
      oe[i] = make_int2(start, start + pad);
      dinv[i] = rsqrtf((float)(c + 1));
    }
  } else {
    int j = (bx - 40) * 256 + tid;
    if (j < 33 * 32){
      int k = j >> 5, c = j & 31;
      float s = 0.f;
      for (int m = 0; m < 64; ++m) s += W1[k * 64 + m] * W2[m * 32 + c];
      W12[j] = s;
    } else if (j < 33 * 32 + 32){
      int c = j - 33 * 32;
      float s = 0.f;
      for (int m = 0; m < 64; ++m) s += b1[m] * W2[m * 32 + c];
      bb[c] = s;
    }
  }
}

// ---- FUSED scatter + GEMM1 dispatch ----------------------------------------
// scatter (blocks [0,SB)) and gemm1 (blocks [SB,SB+3840)) are independent.
// GEMM1 v5: direct-to-LDS staging (global_load_lds, width=16), XOR bank
// swizzle on the SOURCE address, conflict-free ds_read_b128. LDS = 32 KiB.
__global__ __launch_bounds__(256) void k_fused(
    const int* __restrict__ ei, const int2* __restrict__ oe,
    int* __restrict__ cur, const float* __restrict__ dinv,
    unsigned* __restrict__ csr, float* __restrict__ srow, int E, int SB,
    const float* __restrict__ x, const float* __restrict__ mask,
    const float* __restrict__ W12, unsigned* __restrict__ hw){
  __shared__ float xs[256][32];               // [node][feat], XOR-swizzled
  const int bx = blockIdx.x;
  const int t  = threadIdx.x;
  if (bx < SB){
    // ---- scatter path (also accumulates srow_acc[d] = sum dinv[src]) ----
    int e = bx * 256 + t;
    if (e >= E) return;
    int s = ei[e], d = ei[E + e];
    float ds = dinv[s];
    int pos = oe[d].x + atomicAdd(&cur[d], 1);
    csr[pos] = ((unsigned)s << 16) | (unsigned)f2h(ds);
    atomicAdd(&srow[d], ds);
    return;
  }
  // ---- gemm1 path ----
  const int g  = bx - SB;                     // 0..3839
  const int pg = g / 40;                      // 0..95 (b*24+h)
  const int n0 = (g % 40) * 256;
  const int l  = t & 63;
  const int wv = __builtin_amdgcn_readfirstlane(t) >> 6;   // wave-uniform
  const int grp = pg >> 2, p = pg & 3;
  const float mv = mask[pg];
  const f32x2* Wp = (const f32x2*)W12;        // [33][16] feature pairs
  f32x2 acc[16];
  #pragma unroll
  for (int qf = 0; qf < 16; ++qf){
    f32x2 w = Wp[32 * 16 + qf];               // mask row
    acc[qf].x = mv * w.x; acc[qf].y = mv * w.y;
  }
  // stage: each wave issues 8 global_load_lds, each covering 8 rows (1 KB)
  const int rsub = l >> 3;                    // row within 8-row chunk
  const int qd   = (l & 7) ^ rsub;            // pre-swizzled source quad
  const float* xpg = x + (size_t)pg * (NN * FF);
  #pragma unroll
  for (int i = 0; i < 8; ++i){
    int chunk = wv * 8 + i;                   // 0..31, wave-uniform
    int grow = n0 + chunk * 8 + rsub;
    grow = grow < NN ? grow : NN - 1;         // clamp: dup rows unused
    const float* gsrc = xpg + (size_t)grow * FF + (qd << 2);
    char* ldst = (char*)&xs[0][0] + (chunk << 10);   // wave-uniform base
    __builtin_amdgcn_global_load_lds(
        (const __attribute__((address_space(1))) void*)gsrc,
        (__attribute__((address_space(3))) void*)ldst, 16, 0, 0);
  }
  asm volatile("s_waitcnt vmcnt(0)" ::: "memory");
  __syncthreads();
  const int n = n0 + t;
  if (n >= NN) return;
  const int sw = (t & 7) << 2;
  #pragma unroll
  for (int Q = 0; Q < 8; ++Q){
    float4 v = *(const float4*)&xs[t][(Q << 2) ^ sw];
    const float* vf = (const float*)&v;
    #pragma unroll
    for (int j = 0; j < 4; ++j){
      int k = (Q << 2) + j;
      f32x2 xk2; xk2.x = vf[j]; xk2.y = vf[j];
      #pragma unroll
      for (int qf = 0; qf < 16; ++qf) pkfma(acc[qf], Wp[k * 16 + qf], xk2);
    }
  }
  unsigned* hwg = hw + (size_t)grp * (NN * 64) + ((size_t)n << 6) + (p << 4);
  #pragma unroll
  for (int j = 0; j < 4; ++j){
    uint4 u;
    u.x = (unsigned)f2h(acc[4*j+0].x) | ((unsigned)f2h(acc[4*j+0].y) << 16);
    u.y = (unsigned)f2h(acc[4*j+1].x) | ((unsigned)f2h(acc[4*j+1].y) << 16);
    u.z = (unsigned)f2h(acc[4*j+2].x) | ((unsigned)f2h(acc[4*j+2].y) << 16);
    u.w = (unsigned)f2h(acc[4*j+3].x) | ((unsigned)f2h(acc[4*j+3].y) << 16);
    ((uint4*)hwg)[j] = u;
  }
}

// ---- block->group mapping: pin each group to one XCD (blockIdx%8) ----------
__device__ __forceinline__ void map_block(int bx, int& grp, int& chunk){
  int r  = bx / 5000;       // 0..2
  int w8 = bx % 5000;
  grp   = r * 8 + (w8 & 7);
  chunk = w8 >> 3;          // 0..624
}

// ---- 4-deep pipelined edge aggregation, DUAL accumulator chains ------------
// All fmix previously accumulated into ONE (ax,ay) -> 16-deep serial VALU
// dependency chain per iteration (~4cy each) that waves couldn't fill around
// their vmcnt stalls (VALUBusy 55% with nothing saturated). Now quads A,C
// feed chain0 (ax,ay) and B,D feed chain1 (bx,by) -- consecutive steps
// alternate chains, halving dependent latency; merged once per node.
#define ROWB(w) ((((unsigned)(w)) >> 8) & 0xFFFF00u)
__device__ __forceinline__ void agg_edges(int e0, int e1,
    const unsigned* __restrict__ csr, const char* __restrict__ Vb, int loff,
    float& ax, float& ay, float& bx, float& by){
  int nq = (e1 - e0) >> 2;
  if (nq <= 0) return;
  const int4* c4 = (const int4*)(csr + e0);   // 16 B per quad
  const int qlast = nq - 1;
  #define VLD(w) (*(const unsigned*)(Vb + (unsigned)(ROWB(w) + loff)))
  int4 cA, cB, cC, cD;          // csr quads q..q+3   (fmix source)
  int4 cA2, cB2, cC2, cD2;      // csr quads q+4..q+7 (gather-address source)
  int4 cA3, cB3, cC3, cD3;      // csr quads q+8..q+11 (in-flight window)
  unsigned rA0,rA1,rA2,rA3, rB0,rB1,rB2,rB3;
  unsigned rC0,rC1,rC2,rC3, rD0,rD1,rD2,rD3;
  {
    int i1 = 1<=qlast?1:qlast, i2 = 2<=qlast?2:qlast, i3 = 3<=qlast?3:qlast;
    cA = c4[0]; cB = c4[i1]; cC = c4[i2]; cD = c4[i3];
    int i4 = 4<=qlast?4:qlast, i5 = 5<=qlast?5:qlast;
    int i6 = 6<=qlast?6:qlast, i7 = 7<=qlast?7:qlast;
    cA2 = c4[i4]; cB2 = c4[i5]; cC2 = c4[i6]; cD2 = c4[i7];
    int i8 = 8<=qlast?8:qlast, i9 = 9<=qlast?9:qlast;
    int i10 = 10<=qlast?10:qlast, i11 = 11<=qlast?11:qlast;
    cA3 = c4[i8]; cB3 = c4[i9]; cC3 = c4[i10]; cD3 = c4[i11];
    rA0 = VLD(cA.x); rA1 = VLD(cA.y); rA2 = VLD(cA.z); rA3 = VLD(cA.w);
    rB0 = VLD(cB.x); rB1 = VLD(cB.y); rB2 = VLD(cB.z); rB3 = VLD(cB.w);
    rC0 = VLD(cC.x); rC1 = VLD(cC.y); rC2 = VLD(cC.z); rC3 = VLD(cC.w);
    rD0 = VLD(cD.x); rD1 = VLD(cD.y); rD2 = VLD(cD.z); rD3 = VLD(cD.w);
  }
  int q = 0;
  #define AGG_STEP(AX, AY, cX, cX2, cX3, r0, r1, r2, r3)                \
    do {                                                                \
      fmix2p(AX, AY, (unsigned)cX.x, r0);                               \
      fmix2p(AX, AY, (unsigned)cX.y, r1);                               \
      fmix2p(AX, AY, (unsigned)cX.z, r2);                               \
      fmix2p(AX, AY, (unsigned)cX.w, r3);                               \
      r0 = VLD(cX2.x); r1 = VLD(cX2.y);                                 \
      r2 = VLD(cX2.z); r3 = VLD(cX2.w);                                 \
      cX = cX2; cX2 = cX3;                                              \
    } while (0)
  for (; q + 3 < nq; q += 4){
    AGG_STEP(ax, ay, cA, cA2, cA3, rA0,rA1,rA2,rA3);
    AGG_STEP(bx, by, cB, cB2, cB3, rB0,rB1,rB2,rB3);
    AGG_STEP(ax, ay, cC, cC2, cC3, rC0,rC1,rC2,rC3);
    AGG_STEP(bx, by, cD, cD2, cD3, rD0,rD1,rD2,rD3);
    int j0 = q+12 <= qlast ? q+12 : qlast;
    int j1 = q+13 <= qlast ? q+13 : qlast;
    int j2 = q+14 <= qlast ? q+14 : qlast;
    int j3 = q+15 <= qlast ? q+15 : qlast;
    cA3 = c4[j0]; cB3 = c4[j1]; cC3 = c4[j2]; cD3 = c4[j3];
  }
  #undef AGG_STEP
  #undef VLD
  int rem = nq - q;   // 0..3 (wave-uniform)
  if (rem > 0){
    fmix2p(ax, ay, (unsigned)cA.x, rA0);
    fmix2p(ax, ay, (unsigned)cA.y, rA1);
    fmix2p(ax, ay, (unsigned)cA.z, rA2);
    fmix2p(ax, ay, (unsigned)cA.w, rA3);
  }
  if (rem > 1){
    fmix2p(bx, by, (unsigned)cB.x, rB0);
    fmix2p(bx, by, (unsigned)cB.y, rB1);
    fmix2p(bx, by, (unsigned)cB.z, rB2);
    fmix2p(bx, by, (unsigned)cB.w, rB3);
  }
  if (rem > 2){
    fmix2p(ax, ay, (unsigned)cC.x, rC0);
    fmix2p(ax, ay, (unsigned)cC.y, rC1);
    fmix2p(ax, ay, (unsigned)cC.z, rC2);
    fmix2p(ax, ay, (unsigned)cC.w, rC3);
  }
}

// ---- agg layer 1: t1 = A*hw (fp16 rows, fp32 accum) ------------------------
__global__ __launch_bounds__(256) void k_agg1(const int2* __restrict__ oe,
    const unsigned* __restrict__ csr, const float* __restrict__ dinv,
    const unsigned int* __restrict__ V, unsigned int* __restrict__ T){
  int grp, chunk; map_block(blockIdx.x, grp, chunk);
  int tid = threadIdx.x;
  int l = tid & 63;
  int wv = __builtin_amdgcn_readfirstlane(tid) >> 6;   // wave-uniform
  const char* Vb = (const char*)(V + (size_t)grp * (NN * 64));
  unsigned int* Tg = T + (size_t)grp * (NN * 64);
  int loff = l * 4;
  for (int it = 0; it < 4; ++it){
    int n = chunk * 16 + wv * 4 + it;
    float din = dinv[n];
    int2 ee = oe[n];
    unsigned sv = *(const unsigned*)(Vb + (unsigned)((n << 8) + loff));
    float ax = 0.f, ay = 0.f, bx = 0.f, by = 0.f;
    fmix2s(ax, ay, din, sv);
    agg_edges(ee.x, ee.y, csr, Vb, loff, ax, ay, bx, by);
    ax += bx; ay += by;
    Tg[((size_t)n << 6) + l] =
        (unsigned)f2h(din * ax) | ((unsigned)f2h(din * ay) << 16);
  }
}

// ---- agg layer 2 + epilogue: out = tanh(A*t1 + srow*bb + b2) fp32 ----------
__global__ __launch_bounds__(256) void k_agg2(const int2* __restrict__ oe,
    const unsigned* __restrict__ csr, const float* __restrict__ dinv,
    const float* __restrict__ srow, const float* __restrict__ bb,
    const float* __restrict__ b2, const unsigned int* __restrict__ V,
    float* __restrict__ out){
  int grp, chunk; map_block(blockIdx.x, grp, chunk);
  int tid = threadIdx.x;
  int l = tid & 63;
  int wv = __builtin_amdgcn_readfirstlane(tid) >> 6;
  int p = l >> 4, fi = l & 15;
  const char* Vb = (const char*)(V + (size_t)grp * (NN * 64));
  int pg = grp * PG + p;
  float2 bbq = ((const float2*)bb)[fi];
  float2 b2q = ((const float2*)b2)[fi];
  float* outp = out + (size_t)pg * (NN * FF);
  int loff = l * 4;
  for (int it = 0; it < 4; ++it){
    int n = chunk * 16 + wv * 4 + it;
    float din = dinv[n];
    int2 ee = oe[n];
    unsigned sv = *(const unsigned*)(Vb + (unsigned)((n << 8) + loff));
    float ax = 0.f, ay = 0.f, bx = 0.f, by = 0.f;
    fmix2s(ax, ay, din, sv);
    agg_edges(ee.x, ee.y, csr, Vb, loff, ax, ay, bx, by);
    ax += bx; ay += by;
    float sr = din * (din + srow[n]);   // srow reconstructed from scatter acc
    float2 o;
    o.x = tanhf(din * ax + sr * bbq.x + b2q.x);
    o.y = tanhf(din * ay + sr * bbq.y + b2q.y);
    ((float2*)(outp + (size_t)n * FF))[fi] = o;
  }
}

extern "C" void kernel_launch(void* const* d_in, const int* in_sizes, int n_in,
                              void* d_out, int out_size, void* d_ws, size_t ws_size,
                              hipStream_t stream){
  const float* x    = (const float*)d_in[0];
  const float* mask = (const float*)d_in[1];
  const int*   ei   = (const int*)d_in[2];
  const float* W1   = (const float*)d_in[3];
  const float* b1   = (const float*)d_in[4];
  const float* W2   = (const float*)d_in[5];
  const float* b2   = (const float*)d_in[6];
  float* out = (float*)d_out;
  const int E = in_sizes[2] / 2;   // 320000
  const int CSRCAP = E + 3 * NN + 64;  // padded-to-4 worst case + slack (entries)
  const int SB = (E + 255) / 256;      // scatter blocks

  char* wsp = (char*)d_ws;
  auto alloc = [&](size_t bytes) -> char* {
    char* p = wsp; wsp += (bytes + 255) & ~(size_t)255; return p;
  };
  // zero-span buffers first (cnt..csr zeroed by ONE memset)
  int*   cnt  = (int*)  alloc((size_t)NN * 4);
  int*   cur  = (int*)  alloc((size_t)NN * 4);
  float* srow = (float*)alloc((size_t)NN * 4);
  int*   gtop = (int*)  alloc(256);
  unsigned* csr = (unsigned*)alloc((size_t)CSRCAP * 4);
  float* dinv = (float*)alloc((size_t)NN * 4);
  int2*  oe   = (int2*) alloc((size_t)NN * 8);
  float* W12  = (float*)alloc(33 * 32 * 4);
  float* bbv  = (float*)alloc(32 * 4);
  const size_t per_group = (size_t)NN * 64 * 4;    // [n][4p][32f] fp16 = 2.56MB
  unsigned int* hw = (unsigned int*)alloc((size_t)NGRP * per_group);
  unsigned int* t1 = (unsigned int*)alloc((size_t)NGRP * per_group);

  size_t zspan = (size_t)((char*)dinv - (char*)cnt);
  hipMemsetAsync(cnt, 0, zspan, stream);               // cnt+cur+srow+gtop+csr
  k_count<<<SB, 256, 0, stream>>>(ei + E, cnt, E);
  k_prep <<<45, 256, 0, stream>>>(cnt, oe, dinv, gtop, W1, W2, b1, W12, bbv);
  k_fused<<<SB + 3840, 256, 0, stream>>>(ei, oe, cur, dinv, csr, srow, E, SB,
                                         x, mask, W12, hw);
  k_agg1 <<<15000, 256, 0, stream>>>(oe, csr, dinv, hw, t1);
  k_agg2 <<<15000, 256, 0, stream>>>(oe, csr, dinv, srow, bbv, b2, t1, out);
}